// Round 9
// baseline (237.651 us; speedup 1.0000x reference)
//
#include <hip/hip_runtime.h>

#define B_ 4
#define T_ 2048
#define C_ 1024

typedef unsigned short u16;
typedef unsigned int u32;
typedef short sh8 __attribute__((ext_vector_type(8)));   // 8 bf16 payload (4 VGPRs)
typedef float f32x4 __attribute__((ext_vector_type(4)));

// row sums of P = exp(S): written by scores blocks (atomics), read by pv blocks.
// row_done_g[b*16+m]: number of completed scores tiles in row m of batch b.
// Both zeroed by cvt_all each iteration (graph-replay safe).
__device__ float rowsum_g[4 * 2048];
__device__ int   row_done_g[64];

__device__ __forceinline__ float bf2f(u16 u) {
    union { float f; u32 i; } c; c.i = ((u32)u) << 16; return c.f;
}
__device__ __forceinline__ u16 f2bf(float f) {
    union { float f; u32 i; } c; c.f = f;
    return (u16)((c.i + 0x7FFFu + ((c.i >> 16) & 1u)) >> 16);
}

// async 16B/lane global->LDS. Dest = wave-uniform base + lane*16.
__device__ __forceinline__ void gload_lds16(const void* g, void* l) {
    __builtin_amdgcn_global_load_lds(
        (const __attribute__((address_space(1))) u32*)g,
        (__attribute__((address_space(3))) u32*)l, 16, 0, 0);
}

__device__ __forceinline__ void wait_vm8()   { asm volatile("s_waitcnt vmcnt(8)" ::: "memory"); }
__device__ __forceinline__ void wait_vm0()   { asm volatile("s_waitcnt vmcnt(0)" ::: "memory"); }
__device__ __forceinline__ void barrier_raw(){ asm volatile("s_barrier" ::: "memory"); }

// ---------------------------------------------------------------------------
// 128x128 TN MFMA core, bf16, BK=64, DOUBLE-BUFFERED global_load_lds:
//   iter kt:  s_waitcnt vmcnt(8) -> s_barrier -> 32 MFMA on buf[kt&1]
//             -> s_barrier -> DMA tile kt+2 into buf[kt&1]
// LDS: A0 @0, B0 @8192, A1 @16384, B1 @24576 (u16 units) = 64 KB.
// Granule swizzle: phys col = c ^ (row&7), applied in the lane->global mapping.
// Measured (r6 qkv_f): 885 TF chip-wide at 2 blocks/CU, K=1024 -- at the
// structural ceiling for this K (m248 8-phase full stack: 848 TF @ K=1024).
// ---------------------------------------------------------------------------
template<bool RS>
__device__ __forceinline__ void mm_core(
    const u16* __restrict__ A, const u16* __restrict__ B,
    int ldA, int ldB, int nk64,
    u16* lds, f32x4 (&acc)[4][4], f32x4* rsacc, int tid)
{
    const int w  = tid >> 6, l = tid & 63;
    const int fr = l & 15,  fq = l >> 4;
    const int wm = (w & 1) << 6, wn = (w >> 1) << 6;
    const int rl = l >> 3;            // row within 8-row group
    const int pc = l & 7;             // phys granule col this lane fills
    const int cg = pc ^ rl;           // logical granule to fetch

    sh8 ones;
    if (RS) {
#pragma unroll
        for (int e = 0; e < 8; ++e) ones[e] = (short)0x3F80;  // bf16 1.0
    }

    auto issue = [&](int kt) {
        const int ko = kt << 6;
        u16* dA = lds + ((kt & 1) << 14);
        u16* dB = dA + 8192;
#pragma unroll
        for (int t = 0; t < 4; ++t) {
            const int r0 = w * 32 + t * 8;
            const int r  = r0 + rl;
            gload_lds16(A + (size_t)r * ldA + ko + cg * 8, dA + ((size_t)r0 * 8 + l) * 8);
            gload_lds16(B + (size_t)r * ldB + ko + cg * 8, dB + ((size_t)r0 * 8 + l) * 8);
        }
    };

    issue(0);
    issue(1);

    for (int kt = 0; kt < nk64; ++kt) {
        if (kt + 1 < nk64) wait_vm8(); else wait_vm0();
        barrier_raw();                       // block-wide: tile kt resident
        u16* bufA = lds + ((kt & 1) << 14);
        u16* bufB = bufA + 8192;
#pragma unroll
        for (int kk = 0; kk < 2; ++kk) {
            sh8 af[4], bf[4];
            const int g = kk * 4 + fq;
#pragma unroll
            for (int i = 0; i < 4; ++i) {
                const int m = wm + i * 16 + fr;
                af[i] = *(const sh8*)(bufA + ((size_t)m * 8 + (g ^ (m & 7))) * 8);
                const int n = wn + i * 16 + fr;
                bf[i] = *(const sh8*)(bufB + ((size_t)n * 8 + (g ^ (n & 7))) * 8);
            }
#pragma unroll
            for (int i = 0; i < 4; ++i) {
#pragma unroll
                for (int j = 0; j < 4; ++j)
                    acc[i][j] = __builtin_amdgcn_mfma_f32_16x16x32_bf16(af[i], bf[j], acc[i][j], 0, 0, 0);
                if (RS)
                    rsacc[i] = __builtin_amdgcn_mfma_f32_16x16x32_bf16(af[i], ones, rsacc[i], 0, 0, 0);
            }
        }
        barrier_raw();                       // all waves done reading buf[kt&1]
        if (kt + 2 < nk64) issue(kt + 2);
    }
}

// --------------------- conversions (fused) ----------------------------------
// blocks [0,8192): x fp32 -> bf16.  [8192,8960): W -> W^T bf16 (x3).
// [8960,8962): zero rowsum_g + row_done_g (must precede att_fused's atomics).
__global__ __launch_bounds__(256) void cvt_all(
    const float* __restrict__ x,
    const float* __restrict__ Wq, const float* __restrict__ Wk, const float* __restrict__ Wv,
    u16* __restrict__ xb, u16* __restrict__ wt)
{
    __shared__ float tile[64][68];
    const int bid = blockIdx.x;
    if (bid >= 8960) {
        float* p = rowsum_g + (size_t)(bid - 8960) * 4096 + threadIdx.x * 16;
        const float4 z4 = {0.f, 0.f, 0.f, 0.f};
#pragma unroll
        for (int e = 0; e < 4; ++e) ((float4*)p)[e] = z4;
        if (bid == 8960 && threadIdx.x < 64) row_done_g[threadIdx.x] = 0;
        return;
    }
    if (bid < 8192) {
        size_t i = ((size_t)bid * 256 + threadIdx.x) * 4;
        float4 f = *(const float4*)(x + i);
        ushort4 o;
        o.x = f2bf(f.x); o.y = f2bf(f.y); o.z = f2bf(f.z); o.w = f2bf(f.w);
        *(ushort4*)(xb + i) = o;
        return;
    }
    const int r = bid - 8192;
    const int z = r >> 8;                  // 0..2
    const int rr = r & 255;
    const int n0 = (rr & 15) * 64, k0 = (rr >> 4) * 64;
    const float* W = z == 0 ? Wq : (z == 1 ? Wk : Wv);
    u16* out = wt + (size_t)z * C_ * C_;
    const int tx = threadIdx.x & 15, ty = threadIdx.x >> 4;
#pragma unroll
    for (int rr2 = 0; rr2 < 4; ++rr2) {
        int row = ty + rr2 * 16;
        *(float4*)&tile[row][tx * 4] = *(const float4*)(W + (size_t)(k0 + row) * C_ + n0 + tx * 4);
    }
    __syncthreads();
#pragma unroll
    for (int rr2 = 0; rr2 < 4; ++rr2) {
        int n = ty + rr2 * 16;
        ushort4 o;
        o.x = f2bf(tile[tx * 4 + 0][n]);
        o.y = f2bf(tile[tx * 4 + 1][n]);
        o.z = f2bf(tile[tx * 4 + 2][n]);
        o.w = f2bf(tile[tx * 4 + 3][n]);
        *(ushort4*)(out + (size_t)(n0 + n) * C_ + k0 + tx * 4) = o;
    }
}

// --------------------- q/k/v projections (fused, XCD-local) -----------------
// 1536 blocks = 3 z-groups x 512. Within a group (512%8==0 keeps XCD phase):
//   XCD j = inner&7 owns m-tiles [8j,8j+8) x all 8 n-panels ->
//   per-XCD working set = 2 MB xb slice + 2 MB W panel = 4 MB = L2 size.
//   (Counter evidence r6: FETCH 200 -> 49 MB, dur 71 -> 59 us, 885 TF.)
// z==2 (v) writes TRANSPOSED vt[b][c][t] via LDS bounce.
__global__ __launch_bounds__(256, 2) void qkv_f(
    const u16* __restrict__ xb, const u16* __restrict__ wt,
    const float* __restrict__ bq, const float* __restrict__ bk, const float* __restrict__ bv,
    u16* __restrict__ qo, u16* __restrict__ ko, u16* __restrict__ vto)
{
    __shared__ __align__(16) u16 smem[32768];   // 64 KB: dbuf staging | bounce
    const int x = blockIdx.x;
    const int z = x >> 9;                        // 0..2
    const int inner = x & 511;
    const int mt = ((inner & 7) << 3) + (inner >> 6);   // 8*XCD + slice row
    const int nt = (inner >> 3) & 7;
    const int m0 = mt << 7, n0 = nt << 7;
    const u16* W = wt + (size_t)z * C_ * C_;
    const float* bias = z == 0 ? bq : (z == 1 ? bk : bv);
    const int tid = threadIdx.x;
    f32x4 acc[4][4];
#pragma unroll
    for (int i = 0; i < 4; ++i)
#pragma unroll
        for (int j = 0; j < 4; ++j) acc[i][j] = 0.0f;

    mm_core<false>(xb + (size_t)m0 * C_, W + (size_t)n0 * C_, C_, C_, C_ / 64, smem, acc, nullptr, tid);

    const int w = tid >> 6, l = tid & 63, fr = l & 15, fq = l >> 4;
    const int wm = (w & 1) << 6, wn = (w >> 1) << 6;
    if (z < 2) {
#pragma unroll
        for (int i = 0; i < 4; ++i)
#pragma unroll
            for (int j = 0; j < 4; ++j) {
                const int ln = wn + j * 16 + fr;
                const float bb = bias[n0 + ln];
#pragma unroll
                for (int r = 0; r < 4; ++r) {
                    const int lm = wm + i * 16 + fq * 4 + r;
                    smem[lm * 136 + ln] = f2bf(acc[i][j][r] + bb);
                }
            }
        __syncthreads();
        u16* out = z == 0 ? qo : ko;
        const int rr = tid >> 4, cc = tid & 15;
#pragma unroll
        for (int p = 0; p < 8; ++p) {
            const int row = p * 16 + rr;
            uint4 val = *(const uint4*)&smem[row * 136 + cc * 8];
            *(uint4*)(out + (size_t)(m0 + row) * C_ + n0 + cc * 8) = val;
        }
    } else {
#pragma unroll
        for (int i = 0; i < 4; ++i)
#pragma unroll
            for (int j = 0; j < 4; ++j) {
                const int ln = wn + j * 16 + fr;
                const float bb = bias[n0 + ln];
#pragma unroll
                for (int r = 0; r < 4; ++r) {
                    const int lm = wm + i * 16 + fq * 4 + r;
                    smem[lm * 129 + ln] = f2bf(acc[i][j][r] + bb);
                }
            }
        __syncthreads();
        const int b = m0 >> 11;
        const int t0 = m0 & 2047;
        u16* vt = vto + (size_t)b * C_ * T_;
#pragma unroll
        for (int pass = 0; pass < 8; ++pass) {
            const int ln = (tid >> 4) + pass * 16;
            const int c  = tid & 15;
            u16 tmp[8];
#pragma unroll
            for (int e = 0; e < 8; ++e) tmp[e] = smem[(c * 8 + e) * 129 + ln];
            *(uint4*)(vt + (size_t)(n0 + ln) * T_ + t0 + c * 8) = *(uint4*)tmp;
        }
    }
}

// att per-batch offsets in u16 units: b0,b1 over xb region; b2,b3 over wt region.
__device__ __constant__ size_t att_off[4] = {
    0, (size_t)1 << 22, (size_t)1 << 25, ((size_t)1 << 25) + ((size_t)1 << 22)
};

// --------------------- fused attention: scores THEN pv, one dispatch --------
// ids [0,544): scores tiles, rows ordered DESCENDING (row 15 first) so the
//   heaviest pv rows unblock earliest. Epilogue: att write + rowsum atomics,
//   then __threadfence + row_done counter increment (device-scope release).
// ids [544,1056): pv tiles, m DESCENDING (heavy-first). tid0 spins on
//   row_done[b][m] == m+1 (s_sleep backoff), __threadfence acquire, then the
//   proven BK=64 core. In-order workgroup dispatch => all scores blocks
//   launch before any pv block; spinners (<=512 pv) always coexist with
//   running scores blocks => no deadlock; pv heavies backfill scores' 32-tile
//   tail that previously idled ~220 CUs behind a stream drain.
__global__ __launch_bounds__(256, 2) void att_fused(
    const u16* __restrict__ qb, const u16* __restrict__ kb,
    const u16* __restrict__ vt, u16* __restrict__ wsbase,
    float* __restrict__ outp)
{
    __shared__ __align__(16) u16 smem[32768];   // 64 KB: dbuf staging | bounce
    const int id = blockIdx.x;
    const int tid = threadIdx.x;

    if (id < 544) {
        // ---------------- scores tile ----------------
        int r = 15, off = 0;
        while (id >= off + 4 * (r + 1)) { off += 4 * (r + 1); --r; }
        const int rem = id - off;
        const int b = rem & 3, bx = rem >> 2, by = r;
        const int s0 = bx * 128, m0 = by * 128;
        const u16* Q = qb + (size_t)b * T_ * C_ + (size_t)m0 * C_;
        const u16* K = kb + (size_t)b * T_ * C_ + (size_t)s0 * C_;
        f32x4 acc[4][4];
#pragma unroll
        for (int i = 0; i < 4; ++i)
#pragma unroll
            for (int j = 0; j < 4; ++j) acc[i][j] = 0.0f;

        mm_core<false>(Q, K, C_, C_, C_ / 64, smem, acc, nullptr, tid);

        const int w = tid >> 6, l = tid & 63, fr = l & 15, fq = l >> 4;
        const int wm = (w & 1) << 6, wn = (w >> 1) << 6;
#pragma unroll
        for (int i = 0; i < 4; ++i)
#pragma unroll
            for (int rr = 0; rr < 4; ++rr) {
                const int lm = wm + i * 16 + fq * 4 + rr;
                const int m = m0 + lm;
#pragma unroll
                for (int j = 0; j < 4; ++j) {
                    const int ls = wn + j * 16 + fr;
                    const int s = s0 + ls;
                    float e = (s <= m) ? __expf(acc[i][j][rr] * 0.03125f) : 0.f;
                    smem[lm * 136 + ls] = f2bf(e);
                }
            }
        __syncthreads();
        u16* att = wsbase + att_off[b] + (size_t)m0 * T_ + s0;
        {
            const int rr = tid >> 4, cc = tid & 15;
#pragma unroll
            for (int p = 0; p < 8; ++p) {
                const int row = p * 16 + rr;
                uint4 val = *(const uint4*)&smem[row * 136 + cc * 8];
                *(uint4*)(att + (size_t)row * T_ + cc * 8) = val;
            }
        }
        // P row-sums from the bounce tile (bf16-rounded, matches what pv reads)
        {
            const int r2 = tid >> 1, half = tid & 1;
            const u16* rowp = &smem[r2 * 136 + half * 64];
            float ssum = 0.f;
#pragma unroll
            for (int e = 0; e < 64; ++e) ssum += bf2f(rowp[e]);
            ssum += __shfl_xor(ssum, 1);
            if (!half) atomicAdd(&rowsum_g[b * 2048 + m0 + r2], ssum);
        }
        __syncthreads();                     // all stores/atomics issued & drained
        if (tid == 0) {
            __threadfence();                 // release: writeback L2, order atomics
            atomicAdd(&row_done_g[b * 16 + by], 1);
        }
    } else {
        // ---------------- pv tile ----------------
        const int pid = id - 544;
        const int m = 15 - (pid >> 5);
        const int rem = pid & 31;
        const int b = rem & 3, n = rem >> 2;
        const int n0 = n << 7, m0 = m << 7;

        if (tid == 0) {
            while (atomicAdd(&row_done_g[b * 16 + m], 0) < m + 1)
                __builtin_amdgcn_s_sleep(32);
            __threadfence();                 // acquire: invalidate stale cache
        }
        __syncthreads();

        const u16* A  = wsbase + att_off[b] + (size_t)m0 * T_;
        const u16* Bp = vt + (size_t)b * C_ * T_ + (size_t)n0 * T_;
        f32x4 acc[4][4];
#pragma unroll
        for (int i = 0; i < 4; ++i)
#pragma unroll
            for (int j = 0; j < 4; ++j) acc[i][j] = 0.0f;

        mm_core<false>(A, Bp, T_, T_, (m0 + 128) >> 6, smem, acc, nullptr, tid);

        const int w = tid >> 6, l = tid & 63, fr = l & 15, fq = l >> 4;
        const int wm = (w & 1) << 6, wn = (w >> 1) << 6;
        float* fb = (float*)smem;                  // 64 x 132 f32 bounce (33.8 KB)
#pragma unroll
        for (int p = 0; p < 2; ++p) {
            if ((w & 1) == p) {
#pragma unroll
                for (int i = 0; i < 4; ++i)
#pragma unroll
                    for (int rr = 0; rr < 4; ++rr) {
                        const int rr2 = i * 16 + fq * 4 + rr;
                        const float inv = 1.0f / rowsum_g[b * 2048 + m0 + wm + rr2];
#pragma unroll
                        for (int j = 0; j < 4; ++j)
                            fb[rr2 * 132 + wn + j * 16 + fr] = acc[i][j][rr] * inv;
                    }
            }
            __syncthreads();
            const int rr = tid >> 5, cc = (tid & 31) * 4;
#pragma unroll
            for (int k2 = 0; k2 < 8; ++k2) {
                const int row = k2 * 8 + rr;
                float4 val = *(const float4*)&fb[row * 132 + cc];
                *(float4*)(outp + ((size_t)b * T_ + m0 + p * 64 + row) * C_ + n0 + cc) = val;
            }
            __syncthreads();
        }
    }
}

extern "C" void kernel_launch(void* const* d_in, const int* in_sizes, int n_in,
                              void* d_out, int out_size, void* d_ws, size_t ws_size,
                              hipStream_t stream) {
    const float* x  = (const float*)d_in[0];
    const float* Wq = (const float*)d_in[1];
    const float* bq = (const float*)d_in[2];
    const float* Wk = (const float*)d_in[3];
    const float* bk = (const float*)d_in[4];
    const float* Wv = (const float*)d_in[5];
    const float* bv = (const float*)d_in[6];
    float* out = (float*)d_out;

    // workspace (80 MB):
    //   [ 0,16M) xb   -> dead after qkv; att batches 0,1 overlay
    //   [16,32M) q
    //   [32,48M) k
    //   [48,64M) vt   (v transposed [b][c][t])
    //   [64,70M) wt   -> dead after qkv; att batches 2,3 overlay [64,80M)
    char* ws = (char*)d_ws;
    u16* xb   = (u16*)ws;
    u16* q    = (u16*)(ws + (16ull << 20));
    u16* k    = (u16*)(ws + (32ull << 20));
    u16* vt   = (u16*)(ws + (48ull << 20));
    u16* wt   = (u16*)(ws + (64ull << 20));
    u16* attb = (u16*)ws;   // att_off[] indexes from workspace base

    cvt_all  <<<8962, 256, 0, stream>>>(x, Wq, Wk, Wv, xb, wt);
    qkv_f    <<<1536, 256, 0, stream>>>(xb, wt, bq, bk, bv, q, k, vt);
    att_fused<<<1056, 256, 0, stream>>>(q, k, vt, attb, out);
}

// Round 10
// 212.110 us; speedup vs baseline: 1.1204x; 1.1204x over previous
//
#include <hip/hip_runtime.h>

#define B_ 4
#define T_ 2048
#define C_ 1024

typedef unsigned short u16;
typedef unsigned int u32;
typedef short sh8 __attribute__((ext_vector_type(8)));   // 8 bf16 payload (4 VGPRs)
typedef float f32x4 __attribute__((ext_vector_type(4)));

// row sums of P = exp(S): written by scores (atomics), read by pv.
// Zeroed by cvt_all each iteration (graph-replay safe).
__device__ float rowsum_g[4 * 2048];

__device__ __forceinline__ float bf2f(u16 u) {
    union { float f; u32 i; } c; c.i = ((u32)u) << 16; return c.f;
}
__device__ __forceinline__ u16 f2bf(float f) {
    union { float f; u32 i; } c; c.f = f;
    return (u16)((c.i + 0x7FFFu + ((c.i >> 16) & 1u)) >> 16);
}

// async 16B/lane global->LDS. Dest = wave-uniform base + lane*16.
__device__ __forceinline__ void gload_lds16(const void* g, void* l) {
    __builtin_amdgcn_global_load_lds(
        (const __attribute__((address_space(1))) u32*)g,
        (__attribute__((address_space(3))) u32*)l, 16, 0, 0);
}

__device__ __forceinline__ void wait_vm8()   { asm volatile("s_waitcnt vmcnt(8)" ::: "memory"); }
__device__ __forceinline__ void wait_vm0()   { asm volatile("s_waitcnt vmcnt(0)" ::: "memory"); }
__device__ __forceinline__ void barrier_raw(){ asm volatile("s_barrier" ::: "memory"); }

// ---------------------------------------------------------------------------
// 128x128 TN MFMA core, bf16, BK=64, DOUBLE-BUFFERED global_load_lds:
//   iter kt:  s_waitcnt vmcnt(8) -> s_barrier -> 32 MFMA on buf[kt&1]
//             -> s_barrier -> DMA tile kt+2 into buf[kt&1]
// LDS: A0 @0, B0 @8192, A1 @16384, B1 @24576 (u16 units) = 64 KB.
// Granule swizzle: phys col = c ^ (row&7), applied in the lane->global mapping.
// Measured (r6 qkv_f): 885 TF chip-wide at 2 blocks/CU, K=1024 -- at the
// structural ceiling for this K (m248 8-phase full stack: 848 TF @ K=1024).
// SESSION LESSONS (counter-verified):
//  - XCD-local block mapping is the big L2 lever (FETCH 200->49 MB, r6).
//  - In-kernel cross-phase handshake loses ~24 us to per-block device fences
//    (L2 wb/inv x ~1000 blocks); kernel-boundary sync is cheaper (r9).
//  - Compact BK=32 cores run at half rate regardless of occupancy (r5).
// ---------------------------------------------------------------------------
template<bool RS>
__device__ __forceinline__ void mm_core(
    const u16* __restrict__ A, const u16* __restrict__ B,
    int ldA, int ldB, int nk64,
    u16* lds, f32x4 (&acc)[4][4], f32x4* rsacc, int tid)
{
    const int w  = tid >> 6, l = tid & 63;
    const int fr = l & 15,  fq = l >> 4;
    const int wm = (w & 1) << 6, wn = (w >> 1) << 6;
    const int rl = l >> 3;            // row within 8-row group
    const int pc = l & 7;             // phys granule col this lane fills
    const int cg = pc ^ rl;           // logical granule to fetch

    sh8 ones;
    if (RS) {
#pragma unroll
        for (int e = 0; e < 8; ++e) ones[e] = (short)0x3F80;  // bf16 1.0
    }

    auto issue = [&](int kt) {
        const int ko = kt << 6;
        u16* dA = lds + ((kt & 1) << 14);
        u16* dB = dA + 8192;
#pragma unroll
        for (int t = 0; t < 4; ++t) {
            const int r0 = w * 32 + t * 8;
            const int r  = r0 + rl;
            gload_lds16(A + (size_t)r * ldA + ko + cg * 8, dA + ((size_t)r0 * 8 + l) * 8);
            gload_lds16(B + (size_t)r * ldB + ko + cg * 8, dB + ((size_t)r0 * 8 + l) * 8);
        }
    };

    issue(0);
    issue(1);

    for (int kt = 0; kt < nk64; ++kt) {
        if (kt + 1 < nk64) wait_vm8(); else wait_vm0();
        barrier_raw();                       // block-wide: tile kt resident
        u16* bufA = lds + ((kt & 1) << 14);
        u16* bufB = bufA + 8192;
#pragma unroll
        for (int kk = 0; kk < 2; ++kk) {
            sh8 af[4], bf[4];
            const int g = kk * 4 + fq;
#pragma unroll
            for (int i = 0; i < 4; ++i) {
                const int m = wm + i * 16 + fr;
                af[i] = *(const sh8*)(bufA + ((size_t)m * 8 + (g ^ (m & 7))) * 8);
                const int n = wn + i * 16 + fr;
                bf[i] = *(const sh8*)(bufB + ((size_t)n * 8 + (g ^ (n & 7))) * 8);
            }
#pragma unroll
            for (int i = 0; i < 4; ++i) {
#pragma unroll
                for (int j = 0; j < 4; ++j)
                    acc[i][j] = __builtin_amdgcn_mfma_f32_16x16x32_bf16(af[i], bf[j], acc[i][j], 0, 0, 0);
                if (RS)
                    rsacc[i] = __builtin_amdgcn_mfma_f32_16x16x32_bf16(af[i], ones, rsacc[i], 0, 0, 0);
            }
        }
        barrier_raw();                       // all waves done reading buf[kt&1]
        if (kt + 2 < nk64) issue(kt + 2);
    }
}

// --------------------- conversions (fused) ----------------------------------
// blocks [0,8192): x fp32 -> bf16.  [8192,8960): W -> W^T bf16 (x3).
// [8960,8962): zero rowsum_g (must precede scores' atomics each iteration).
__global__ __launch_bounds__(256) void cvt_all(
    const float* __restrict__ x,
    const float* __restrict__ Wq, const float* __restrict__ Wk, const float* __restrict__ Wv,
    u16* __restrict__ xb, u16* __restrict__ wt)
{
    __shared__ float tile[64][68];
    const int bid = blockIdx.x;
    if (bid >= 8960) {
        float* p = rowsum_g + (size_t)(bid - 8960) * 4096 + threadIdx.x * 16;
        const float4 z4 = {0.f, 0.f, 0.f, 0.f};
#pragma unroll
        for (int e = 0; e < 4; ++e) ((float4*)p)[e] = z4;
        return;
    }
    if (bid < 8192) {
        size_t i = ((size_t)bid * 256 + threadIdx.x) * 4;
        float4 f = *(const float4*)(x + i);
        ushort4 o;
        o.x = f2bf(f.x); o.y = f2bf(f.y); o.z = f2bf(f.z); o.w = f2bf(f.w);
        *(ushort4*)(xb + i) = o;
        return;
    }
    const int r = bid - 8192;
    const int z = r >> 8;                  // 0..2
    const int rr = r & 255;
    const int n0 = (rr & 15) * 64, k0 = (rr >> 4) * 64;
    const float* W = z == 0 ? Wq : (z == 1 ? Wk : Wv);
    u16* out = wt + (size_t)z * C_ * C_;
    const int tx = threadIdx.x & 15, ty = threadIdx.x >> 4;
#pragma unroll
    for (int rr2 = 0; rr2 < 4; ++rr2) {
        int row = ty + rr2 * 16;
        *(float4*)&tile[row][tx * 4] = *(const float4*)(W + (size_t)(k0 + row) * C_ + n0 + tx * 4);
    }
    __syncthreads();
#pragma unroll
    for (int rr2 = 0; rr2 < 4; ++rr2) {
        int n = ty + rr2 * 16;
        ushort4 o;
        o.x = f2bf(tile[tx * 4 + 0][n]);
        o.y = f2bf(tile[tx * 4 + 1][n]);
        o.z = f2bf(tile[tx * 4 + 2][n]);
        o.w = f2bf(tile[tx * 4 + 3][n]);
        *(ushort4*)(out + (size_t)(n0 + n) * C_ + k0 + tx * 4) = o;
    }
}

// --------------------- q/k/v projections (fused, XCD-local) -----------------
// 1536 blocks = 3 z-groups x 512. Within a group (512%8==0 keeps XCD phase):
//   XCD j = inner&7 owns m-tiles [8j,8j+8) x all 8 n-panels ->
//   per-XCD working set = 2 MB xb slice + 2 MB W panel = 4 MB = L2 size.
//   (Counter evidence r6: FETCH 200 -> 49 MB, dur 71 -> 59 us, 885 TF.)
// z==2 (v) writes TRANSPOSED vt[b][c][t] via LDS bounce.
__global__ __launch_bounds__(256, 2) void qkv_f(
    const u16* __restrict__ xb, const u16* __restrict__ wt,
    const float* __restrict__ bq, const float* __restrict__ bk, const float* __restrict__ bv,
    u16* __restrict__ qo, u16* __restrict__ ko, u16* __restrict__ vto)
{
    __shared__ __align__(16) u16 smem[32768];   // 64 KB: dbuf staging | bounce
    const int x = blockIdx.x;
    const int z = x >> 9;                        // 0..2
    const int inner = x & 511;
    const int mt = ((inner & 7) << 3) + (inner >> 6);   // 8*XCD + slice row
    const int nt = (inner >> 3) & 7;
    const int m0 = mt << 7, n0 = nt << 7;
    const u16* W = wt + (size_t)z * C_ * C_;
    const float* bias = z == 0 ? bq : (z == 1 ? bk : bv);
    const int tid = threadIdx.x;
    f32x4 acc[4][4];
#pragma unroll
    for (int i = 0; i < 4; ++i)
#pragma unroll
        for (int j = 0; j < 4; ++j) acc[i][j] = 0.0f;

    mm_core<false>(xb + (size_t)m0 * C_, W + (size_t)n0 * C_, C_, C_, C_ / 64, smem, acc, nullptr, tid);

    const int w = tid >> 6, l = tid & 63, fr = l & 15, fq = l >> 4;
    const int wm = (w & 1) << 6, wn = (w >> 1) << 6;
    if (z < 2) {
#pragma unroll
        for (int i = 0; i < 4; ++i)
#pragma unroll
            for (int j = 0; j < 4; ++j) {
                const int ln = wn + j * 16 + fr;
                const float bb = bias[n0 + ln];
#pragma unroll
                for (int r = 0; r < 4; ++r) {
                    const int lm = wm + i * 16 + fq * 4 + r;
                    smem[lm * 136 + ln] = f2bf(acc[i][j][r] + bb);
                }
            }
        __syncthreads();
        u16* out = z == 0 ? qo : ko;
        const int rr = tid >> 4, cc = tid & 15;
#pragma unroll
        for (int p = 0; p < 8; ++p) {
            const int row = p * 16 + rr;
            uint4 val = *(const uint4*)&smem[row * 136 + cc * 8];
            *(uint4*)(out + (size_t)(m0 + row) * C_ + n0 + cc * 8) = val;
        }
    } else {
#pragma unroll
        for (int i = 0; i < 4; ++i)
#pragma unroll
            for (int j = 0; j < 4; ++j) {
                const int ln = wn + j * 16 + fr;
                const float bb = bias[n0 + ln];
#pragma unroll
                for (int r = 0; r < 4; ++r) {
                    const int lm = wm + i * 16 + fq * 4 + r;
                    smem[lm * 129 + ln] = f2bf(acc[i][j][r] + bb);
                }
            }
        __syncthreads();
        const int b = m0 >> 11;
        const int t0 = m0 & 2047;
        u16* vt = vto + (size_t)b * C_ * T_;
#pragma unroll
        for (int pass = 0; pass < 8; ++pass) {
            const int ln = (tid >> 4) + pass * 16;
            const int c  = tid & 15;
            u16 tmp[8];
#pragma unroll
            for (int e = 0; e < 8; ++e) tmp[e] = smem[(c * 8 + e) * 129 + ln];
            *(uint4*)(vt + (size_t)(n0 + ln) * T_ + t0 + c * 8) = *(uint4*)tmp;
        }
    }
}

// att per-batch offsets in u16 units: b0,b1 over xb region; b2,b3 over wt region.
__device__ __constant__ size_t att_off[4] = {
    0, (size_t)1 << 22, (size_t)1 << 25, ((size_t)1 << 25) + ((size_t)1 << 22)
};

// --------------------- scores: P = exp(q k^T / 32), causal ------------------
// grid (544): XCD-CLUSTERED tile mapping. Dispatch round-robins id%8 across
// XCDs, so seq s = (id&7)*68 + (id>>3) gives each XCD a CONTIGUOUS run of 68
// tiles (batch-major, row-major triangle): Q+K panel footprint ~5.5 MB/XCD.
// Epilogue accumulates P row-sums into rowsum_g (atomics) so pv drops its
// ones-MFMA (-20% pv MFMA). Stream boundary (not in-kernel fence) publishes
// att + rowsum to pv -- r9 proved per-block fences cost ~24 us.
__global__ __launch_bounds__(256, 2) void scores_mfma(
    const u16* __restrict__ qb, const u16* __restrict__ kb, u16* __restrict__ wsbase)
{
    const int id = blockIdx.x;
    const int s_ = (id & 7) * 68 + (id >> 3);   // clustered sequence 0..543
    const int b  = s_ / 136;
    int t = s_ - b * 136;
    int by = (int)((sqrtf(8.f * t + 1.f) - 1.f) * 0.5f);
    while ((by + 1) * (by + 2) / 2 <= t) ++by;
    while (by * (by + 1) / 2 > t) --by;
    const int bx = t - by * (by + 1) / 2;
    const int s0 = bx * 128, m0 = by * 128;
    __shared__ __align__(16) u16 smem[32768];   // 64 KB: dbuf staging | bounce
    const u16* Q = qb + (size_t)b * T_ * C_ + (size_t)m0 * C_;
    const u16* K = kb + (size_t)b * T_ * C_ + (size_t)s0 * C_;
    const int tid = threadIdx.x;
    f32x4 acc[4][4];
#pragma unroll
    for (int i = 0; i < 4; ++i)
#pragma unroll
        for (int j = 0; j < 4; ++j) acc[i][j] = 0.0f;

    mm_core<false>(Q, K, C_, C_, C_ / 64, smem, acc, nullptr, tid);

    const int w = tid >> 6, l = tid & 63, fr = l & 15, fq = l >> 4;
    const int wm = (w & 1) << 6, wn = (w >> 1) << 6;
#pragma unroll
    for (int i = 0; i < 4; ++i)
#pragma unroll
        for (int r = 0; r < 4; ++r) {
            const int lm = wm + i * 16 + fq * 4 + r;
            const int m = m0 + lm;
#pragma unroll
            for (int j = 0; j < 4; ++j) {
                const int ls = wn + j * 16 + fr;
                const int s = s0 + ls;
                float e = (s <= m) ? __expf(acc[i][j][r] * 0.03125f) : 0.f;
                smem[lm * 136 + ls] = f2bf(e);
            }
        }
    __syncthreads();
    u16* att = wsbase + att_off[b] + (size_t)m0 * T_ + s0;
    const int rr = tid >> 4, cc = tid & 15;
#pragma unroll
    for (int p = 0; p < 8; ++p) {
        const int row = p * 16 + rr;
        uint4 val = *(const uint4*)&smem[row * 136 + cc * 8];
        *(uint4*)(att + (size_t)row * T_ + cc * 8) = val;
    }
    // ---- P row-sums from the bounce tile: 2 threads/row, pair-shfl, atomic.
    // Sums the bf16-rounded P (same values pv consumes) -> numerics preserved.
    {
        const int r2 = tid >> 1, half = tid & 1;
        const u16* rowp = &smem[r2 * 136 + half * 64];
        float ssum = 0.f;
#pragma unroll
        for (int e = 0; e < 64; ++e) ssum += bf2f(rowp[e]);
        ssum += __shfl_xor(ssum, 1);
        if (!half) atomicAdd(&rowsum_g[b * 2048 + m0 + r2], ssum);
    }
}

// --------------------- O = (P v) / rowsum -----------------------------------
// grid (8, 16, 4). Rowsum read from rowsum_g (computed by scores) -->
// 32 MFMA per K-step instead of 40 (-20% MFMA).
// PAIR-BALANCED m-tile mapping (r4 counter-verified, -7.7 us): round-robin
// dispatch pairs block i with i+256 on one CU (z differs by 2, same y).
// by = (z<2 ? 15-y : y) makes the pair's K-chunks (16-y)+(y+1) = 17, uniform.
__global__ __launch_bounds__(256, 2) void pv_mfma(
    const u16* __restrict__ wsbase, const u16* __restrict__ vt,
    float* __restrict__ outp)
{
    const int b = blockIdx.z;
    const int n0 = blockIdx.x * 128;
    const int by = (blockIdx.z < 2) ? (15 - blockIdx.y) : blockIdx.y;  // pair-balance
    const int m0 = by * 128;
    __shared__ __align__(16) u16 smem[32768];  // 64 KB: dbuf staging | f32 bounce
    const u16* A  = wsbase + att_off[b] + (size_t)m0 * T_;
    const u16* Bp = vt + (size_t)b * C_ * T_ + (size_t)n0 * T_;
    const int tid = threadIdx.x;
    f32x4 acc[4][4];
#pragma unroll
    for (int i = 0; i < 4; ++i)
#pragma unroll
        for (int j = 0; j < 4; ++j) acc[i][j] = 0.0f;

    mm_core<false>(A, Bp, T_, T_, (m0 + 128) >> 6, smem, acc, nullptr, tid);

    const int w = tid >> 6, l = tid & 63, fr = l & 15, fq = l >> 4;
    const int wm = (w & 1) << 6, wn = (w >> 1) << 6;
    float* fb = (float*)smem;                  // 64 x 132 f32 bounce (33.8 KB)
#pragma unroll
    for (int p = 0; p < 2; ++p) {
        if ((w & 1) == p) {
#pragma unroll
            for (int i = 0; i < 4; ++i)
#pragma unroll
                for (int r = 0; r < 4; ++r) {
                    const int rr2 = i * 16 + fq * 4 + r;
                    const float inv = 1.0f / rowsum_g[b * 2048 + m0 + wm + rr2];
#pragma unroll
                    for (int j = 0; j < 4; ++j)
                        fb[rr2 * 132 + wn + j * 16 + fr] = acc[i][j][r] * inv;
                }
        }
        __syncthreads();
        const int rr = tid >> 5, cc = (tid & 31) * 4;
#pragma unroll
        for (int k2 = 0; k2 < 8; ++k2) {
            const int row = k2 * 8 + rr;
            float4 val = *(const float4*)&fb[row * 132 + cc];
            *(float4*)(outp + ((size_t)b * T_ + m0 + p * 64 + row) * C_ + n0 + cc) = val;
        }
        __syncthreads();
    }
}

extern "C" void kernel_launch(void* const* d_in, const int* in_sizes, int n_in,
                              void* d_out, int out_size, void* d_ws, size_t ws_size,
                              hipStream_t stream) {
    const float* x  = (const float*)d_in[0];
    const float* Wq = (const float*)d_in[1];
    const float* bq = (const float*)d_in[2];
    const float* Wk = (const float*)d_in[3];
    const float* bk = (const float*)d_in[4];
    const float* Wv = (const float*)d_in[5];
    const float* bv = (const float*)d_in[6];
    float* out = (float*)d_out;

    // workspace (80 MB):
    //   [ 0,16M) xb   -> dead after qkv; att batches 0,1 overlay
    //   [16,32M) q
    //   [32,48M) k
    //   [48,64M) vt   (v transposed [b][c][t])
    //   [64,70M) wt   -> dead after qkv; att batches 2,3 overlay [64,80M)
    char* ws = (char*)d_ws;
    u16* xb   = (u16*)ws;
    u16* q    = (u16*)(ws + (16ull << 20));
    u16* k    = (u16*)(ws + (32ull << 20));
    u16* vt   = (u16*)(ws + (48ull << 20));
    u16* wt   = (u16*)(ws + (64ull << 20));
    u16* attb = (u16*)ws;   // att_off[] indexes from workspace base

    cvt_all    <<<8962, 256, 0, stream>>>(x, Wq, Wk, Wv, xb, wt);
    qkv_f      <<<1536, 256, 0, stream>>>(xb, wt, bq, bk, bv, q, k, vt);
    scores_mfma<<<544, 256, 0, stream>>>(q, k, attb);
    pv_mfma    <<<dim3(8, 16, 4), 256, 0, stream>>>(attb, vt, out);
}

// Round 11
// 209.702 us; speedup vs baseline: 1.1333x; 1.0115x over previous
//
#include <hip/hip_runtime.h>

#define B_ 4
#define T_ 2048
#define C_ 1024

typedef unsigned short u16;
typedef unsigned int u32;
typedef short sh8 __attribute__((ext_vector_type(8)));   // 8 bf16 payload (4 VGPRs)
typedef float f32x4 __attribute__((ext_vector_type(4)));

// row sums of P = exp(S): written by scores (atomics), read by pv.
// Zeroed by cvt_all each iteration (graph-replay safe).
__device__ float rowsum_g[4 * 2048];

__device__ __forceinline__ float bf2f(u16 u) {
    union { float f; u32 i; } c; c.i = ((u32)u) << 16; return c.f;
}
__device__ __forceinline__ u16 f2bf(float f) {
    union { float f; u32 i; } c; c.f = f;
    return (u16)((c.i + 0x7FFFu + ((c.i >> 16) & 1u)) >> 16);
}

// async 16B/lane global->LDS. Dest = wave-uniform base + lane*16.
__device__ __forceinline__ void gload_lds16(const void* g, void* l) {
    __builtin_amdgcn_global_load_lds(
        (const __attribute__((address_space(1))) u32*)g,
        (__attribute__((address_space(3))) u32*)l, 16, 0, 0);
}

__device__ __forceinline__ void wait_vm8()   { asm volatile("s_waitcnt vmcnt(8)" ::: "memory"); }
__device__ __forceinline__ void wait_vm6()   { asm volatile("s_waitcnt vmcnt(6)" ::: "memory"); }
__device__ __forceinline__ void wait_vm0()   { asm volatile("s_waitcnt vmcnt(0)" ::: "memory"); }
__device__ __forceinline__ void barrier_raw(){ asm volatile("s_barrier" ::: "memory"); }

// ---------------------------------------------------------------------------
// 128x128 TN MFMA core, bf16, BK=64, DOUBLE-BUFFERED global_load_lds.
// Measured (r6/r10 qkv_f): 885 TF chip-wide at 2 blocks/CU, K=1024 -- at the
// structural ceiling for this K (m248 8-phase full stack: 848 TF @ K=1024).
// SESSION LESSONS (counter-verified):
//  - XCD-local block mapping is the big L2 lever (FETCH 200->49 MB, r6).
//  - In-kernel cross-phase handshake loses ~24 us to per-block device fences
//    (r9); kernel-boundary sync is cheaper.
//  - Compact BK=32 cores run at half rate regardless of occupancy (r5).
//  - Scores pass-quantization (544 blocks / 512 slots) is attacked with
//    half-tiles + 3 blocks/CU (r11, this round), not with handshakes.
// ---------------------------------------------------------------------------
template<bool RS>
__device__ __forceinline__ void mm_core(
    const u16* __restrict__ A, const u16* __restrict__ B,
    int ldA, int ldB, int nk64,
    u16* lds, f32x4 (&acc)[4][4], f32x4* rsacc, int tid)
{
    const int w  = tid >> 6, l = tid & 63;
    const int fr = l & 15,  fq = l >> 4;
    const int wm = (w & 1) << 6, wn = (w >> 1) << 6;
    const int rl = l >> 3;            // row within 8-row group
    const int pc = l & 7;             // phys granule col this lane fills
    const int cg = pc ^ rl;           // logical granule to fetch

    sh8 ones;
    if (RS) {
#pragma unroll
        for (int e = 0; e < 8; ++e) ones[e] = (short)0x3F80;  // bf16 1.0
    }

    auto issue = [&](int kt) {
        const int ko = kt << 6;
        u16* dA = lds + ((kt & 1) << 14);
        u16* dB = dA + 8192;
#pragma unroll
        for (int t = 0; t < 4; ++t) {
            const int r0 = w * 32 + t * 8;
            const int r  = r0 + rl;
            gload_lds16(A + (size_t)r * ldA + ko + cg * 8, dA + ((size_t)r0 * 8 + l) * 8);
            gload_lds16(B + (size_t)r * ldB + ko + cg * 8, dB + ((size_t)r0 * 8 + l) * 8);
        }
    };

    issue(0);
    issue(1);

    for (int kt = 0; kt < nk64; ++kt) {
        if (kt + 1 < nk64) wait_vm8(); else wait_vm0();
        barrier_raw();                       // block-wide: tile kt resident
        u16* bufA = lds + ((kt & 1) << 14);
        u16* bufB = bufA + 8192;
#pragma unroll
        for (int kk = 0; kk < 2; ++kk) {
            sh8 af[4], bf[4];
            const int g = kk * 4 + fq;
#pragma unroll
            for (int i = 0; i < 4; ++i) {
                const int m = wm + i * 16 + fr;
                af[i] = *(const sh8*)(bufA + ((size_t)m * 8 + (g ^ (m & 7))) * 8);
                const int n = wn + i * 16 + fr;
                bf[i] = *(const sh8*)(bufB + ((size_t)n * 8 + (g ^ (n & 7))) * 8);
            }
#pragma unroll
            for (int i = 0; i < 4; ++i) {
#pragma unroll
                for (int j = 0; j < 4; ++j)
                    acc[i][j] = __builtin_amdgcn_mfma_f32_16x16x32_bf16(af[i], bf[j], acc[i][j], 0, 0, 0);
                if (RS)
                    rsacc[i] = __builtin_amdgcn_mfma_f32_16x16x32_bf16(af[i], ones, rsacc[i], 0, 0, 0);
            }
        }
        barrier_raw();                       // all waves done reading buf[kt&1]
        if (kt + 2 < nk64) issue(kt + 2);
    }
}

// ---------------------------------------------------------------------------
// 128x64 HALF-TILE TN core, bf16, BK=64, dbuf, 24 KB/slot = 48 KB LDS total
// -> 3 blocks/CU (144 KB). Same schedule as mm_core (counted vmcnt, granule
// swizzle, 2 barriers/K-step). 6 gloads/thread/slice (4 A + 2 B), steady
// vmcnt(6). Wave layout 2M x 2N over 128x64: per-wave 64x32, acc[4][2].
// Purpose: scores runs 1088 half-blocks on 768 slots -> the 0.25 extra
// block/CU OVERLAPS (3 co-resident) instead of costing a full second pass.
// ---------------------------------------------------------------------------
__device__ __forceinline__ void mm_half(
    const u16* __restrict__ A, const u16* __restrict__ B,
    int ldA, int ldB, int nk64,
    u16* lds, f32x4 (&acc)[4][2], int tid)
{
    const int w  = tid >> 6, l = tid & 63;
    const int fr = l & 15,  fq = l >> 4;
    const int wm = (w & 1) << 6;      // 0 / 64  (M half)
    const int wn = (w >> 1) << 5;     // 0 / 32  (N half of 64)
    const int rl = l >> 3;
    const int pc = l & 7;
    const int cg = pc ^ rl;

    auto issue = [&](int kt) {
        const int ko = kt << 6;
        u16* dA = lds + (kt & 1) * 12288;
        u16* dB = dA + 8192;
#pragma unroll
        for (int t = 0; t < 4; ++t) {                 // A: 128 rows
            const int r0 = w * 32 + t * 8;
            const int r  = r0 + rl;
            gload_lds16(A + (size_t)r * ldA + ko + cg * 8, dA + ((size_t)r0 * 8 + l) * 8);
        }
#pragma unroll
        for (int t = 0; t < 2; ++t) {                 // B: 64 rows
            const int r0 = w * 16 + t * 8;
            const int r  = r0 + rl;
            gload_lds16(B + (size_t)r * ldB + ko + cg * 8, dB + ((size_t)r0 * 8 + l) * 8);
        }
    };

    issue(0);
    issue(1);

    for (int kt = 0; kt < nk64; ++kt) {
        if (kt + 1 < nk64) wait_vm6(); else wait_vm0();
        barrier_raw();                       // slice kt resident block-wide
        const u16* bufA = lds + (kt & 1) * 12288;
        const u16* bufB = bufA + 8192;
#pragma unroll
        for (int kk = 0; kk < 2; ++kk) {
            sh8 af[4], bf[2];
            const int g = kk * 4 + fq;
#pragma unroll
            for (int i = 0; i < 4; ++i) {
                const int m = wm + i * 16 + fr;
                af[i] = *(const sh8*)(bufA + ((size_t)m * 8 + (g ^ (m & 7))) * 8);
            }
#pragma unroll
            for (int j = 0; j < 2; ++j) {
                const int n = wn + j * 16 + fr;
                bf[j] = *(const sh8*)(bufB + ((size_t)n * 8 + (g ^ (n & 7))) * 8);
            }
#pragma unroll
            for (int i = 0; i < 4; ++i) {
                acc[i][0] = __builtin_amdgcn_mfma_f32_16x16x32_bf16(af[i], bf[0], acc[i][0], 0, 0, 0);
                acc[i][1] = __builtin_amdgcn_mfma_f32_16x16x32_bf16(af[i], bf[1], acc[i][1], 0, 0, 0);
            }
        }
        barrier_raw();                       // all waves done with slot kt&1
        if (kt + 2 < nk64) issue(kt + 2);
    }
}

// --------------------- conversions (fused) ----------------------------------
// blocks [0,8192): x fp32 -> bf16.  [8192,8960): W -> W^T bf16 (x3).
// [8960,8962): zero rowsum_g (must precede scores' atomics each iteration).
__global__ __launch_bounds__(256) void cvt_all(
    const float* __restrict__ x,
    const float* __restrict__ Wq, const float* __restrict__ Wk, const float* __restrict__ Wv,
    u16* __restrict__ xb, u16* __restrict__ wt)
{
    __shared__ float tile[64][68];
    const int bid = blockIdx.x;
    if (bid >= 8960) {
        float* p = rowsum_g + (size_t)(bid - 8960) * 4096 + threadIdx.x * 16;
        const float4 z4 = {0.f, 0.f, 0.f, 0.f};
#pragma unroll
        for (int e = 0; e < 4; ++e) ((float4*)p)[e] = z4;
        return;
    }
    if (bid < 8192) {
        size_t i = ((size_t)bid * 256 + threadIdx.x) * 4;
        float4 f = *(const float4*)(x + i);
        ushort4 o;
        o.x = f2bf(f.x); o.y = f2bf(f.y); o.z = f2bf(f.z); o.w = f2bf(f.w);
        *(ushort4*)(xb + i) = o;
        return;
    }
    const int r = bid - 8192;
    const int z = r >> 8;                  // 0..2
    const int rr = r & 255;
    const int n0 = (rr & 15) * 64, k0 = (rr >> 4) * 64;
    const float* W = z == 0 ? Wq : (z == 1 ? Wk : Wv);
    u16* out = wt + (size_t)z * C_ * C_;
    const int tx = threadIdx.x & 15, ty = threadIdx.x >> 4;
#pragma unroll
    for (int rr2 = 0; rr2 < 4; ++rr2) {
        int row = ty + rr2 * 16;
        *(float4*)&tile[row][tx * 4] = *(const float4*)(W + (size_t)(k0 + row) * C_ + n0 + tx * 4);
    }
    __syncthreads();
#pragma unroll
    for (int rr2 = 0; rr2 < 4; ++rr2) {
        int n = ty + rr2 * 16;
        ushort4 o;
        o.x = f2bf(tile[tx * 4 + 0][n]);
        o.y = f2bf(tile[tx * 4 + 1][n]);
        o.z = f2bf(tile[tx * 4 + 2][n]);
        o.w = f2bf(tile[tx * 4 + 3][n]);
        *(ushort4*)(out + (size_t)(n0 + n) * C_ + k0 + tx * 4) = o;
    }
}

// --------------------- q/k/v projections (fused, XCD-local) -----------------
// 1536 blocks = 3 z-groups x 512. Within a group (512%8==0 keeps XCD phase):
//   XCD j = inner&7 owns m-tiles [8j,8j+8) x all 8 n-panels ->
//   per-XCD working set = 2 MB xb slice + 2 MB W panel = 4 MB = L2 size.
//   (Counter evidence r6/r10: FETCH 200 -> 49 MB, dur 71 -> 58 us, 885 TF.)
// z==2 (v) writes TRANSPOSED vt[b][c][t] via LDS bounce.
__global__ __launch_bounds__(256, 2) void qkv_f(
    const u16* __restrict__ xb, const u16* __restrict__ wt,
    const float* __restrict__ bq, const float* __restrict__ bk, const float* __restrict__ bv,
    u16* __restrict__ qo, u16* __restrict__ ko, u16* __restrict__ vto)
{
    __shared__ __align__(16) u16 smem[32768];   // 64 KB: dbuf staging | bounce
    const int x = blockIdx.x;
    const int z = x >> 9;                        // 0..2
    const int inner = x & 511;
    const int mt = ((inner & 7) << 3) + (inner >> 6);   // 8*XCD + slice row
    const int nt = (inner >> 3) & 7;
    const int m0 = mt << 7, n0 = nt << 7;
    const u16* W = wt + (size_t)z * C_ * C_;
    const float* bias = z == 0 ? bq : (z == 1 ? bk : bv);
    const int tid = threadIdx.x;
    f32x4 acc[4][4];
#pragma unroll
    for (int i = 0; i < 4; ++i)
#pragma unroll
        for (int j = 0; j < 4; ++j) acc[i][j] = 0.0f;

    mm_core<false>(xb + (size_t)m0 * C_, W + (size_t)n0 * C_, C_, C_, C_ / 64, smem, acc, nullptr, tid);

    const int w = tid >> 6, l = tid & 63, fr = l & 15, fq = l >> 4;
    const int wm = (w & 1) << 6, wn = (w >> 1) << 6;
    if (z < 2) {
#pragma unroll
        for (int i = 0; i < 4; ++i)
#pragma unroll
            for (int j = 0; j < 4; ++j) {
                const int ln = wn + j * 16 + fr;
                const float bb = bias[n0 + ln];
#pragma unroll
                for (int r = 0; r < 4; ++r) {
                    const int lm = wm + i * 16 + fq * 4 + r;
                    smem[lm * 136 + ln] = f2bf(acc[i][j][r] + bb);
                }
            }
        __syncthreads();
        u16* out = z == 0 ? qo : ko;
        const int rr = tid >> 4, cc = tid & 15;
#pragma unroll
        for (int p = 0; p < 8; ++p) {
            const int row = p * 16 + rr;
            uint4 val = *(const uint4*)&smem[row * 136 + cc * 8];
            *(uint4*)(out + (size_t)(m0 + row) * C_ + n0 + cc * 8) = val;
        }
    } else {
#pragma unroll
        for (int i = 0; i < 4; ++i)
#pragma unroll
            for (int j = 0; j < 4; ++j) {
                const int ln = wn + j * 16 + fr;
                const float bb = bias[n0 + ln];
#pragma unroll
                for (int r = 0; r < 4; ++r) {
                    const int lm = wm + i * 16 + fq * 4 + r;
                    smem[lm * 129 + ln] = f2bf(acc[i][j][r] + bb);
                }
            }
        __syncthreads();
        const int b = m0 >> 11;
        const int t0 = m0 & 2047;
        u16* vt = vto + (size_t)b * C_ * T_;
#pragma unroll
        for (int pass = 0; pass < 8; ++pass) {
            const int ln = (tid >> 4) + pass * 16;
            const int c  = tid & 15;
            u16 tmp[8];
#pragma unroll
            for (int e = 0; e < 8; ++e) tmp[e] = smem[(c * 8 + e) * 129 + ln];
            *(uint4*)(vt + (size_t)(n0 + ln) * T_ + t0 + c * 8) = *(uint4*)tmp;
        }
    }
}

// att per-batch offsets in u16 units: b0,b1 over xb region; b2,b3 over wt region.
__device__ __constant__ size_t att_off[4] = {
    0, (size_t)1 << 22, (size_t)1 << 25, ((size_t)1 << 25) + ((size_t)1 << 22)
};

// --------------------- scores: P = exp(q k^T / 32), causal (half-tiles) -----
// grid (1088): 544 tiles x 2 N-halves, each block 128(M) x 64(S), K=1024.
// 48 KB LDS -> 3 blocks/CU -> 768 slots: 1088 blocks = 4.25 blocks/CU with
// 3-way overlap -> wall ~ work/throughput (~22-25 us) instead of the 2-pass
// 38.6 us quantization wall of 544 full tiles on 512 slots (r10).
// XCD clustering: seq = (id&7)*136 + (id>>3); consecutive seq = the two
// halves of one tile (shared Q panel, same XCD -> L2-hot).
// Epilogue: exp+mask -> att store + 64-col partial row-sums into rowsum_g.
__global__ __launch_bounds__(256, 3) void scores_h(
    const u16* __restrict__ qb, const u16* __restrict__ kb, u16* __restrict__ wsbase)
{
    const int id  = blockIdx.x;
    const int seq = (id & 7) * 136 + (id >> 3);   // 0..1087, XCD-clustered
    const int s_  = seq >> 1;                     // tile index 0..543
    const int hsel= seq & 1;                      // N-half
    const int b   = s_ / 136;
    int t = s_ - b * 136;
    int by = (int)((sqrtf(8.f * t + 1.f) - 1.f) * 0.5f);
    while ((by + 1) * (by + 2) / 2 <= t) ++by;
    while (by * (by + 1) / 2 > t) --by;
    const int bx = t - by * (by + 1) / 2;
    const int m0 = by * 128;
    const int s0 = bx * 128 + hsel * 64;          // this block's 64-col base
    __shared__ __align__(16) u16 smem[24576];     // 48 KB: 2 x 12288 dbuf | bounce
    const u16* Q = qb + (size_t)b * T_ * C_ + (size_t)m0 * C_;
    const u16* K = kb + (size_t)b * T_ * C_ + (size_t)s0 * C_;
    const int tid = threadIdx.x;
    f32x4 acc[4][2];
#pragma unroll
    for (int i = 0; i < 4; ++i) {
        acc[i][0] = 0.0f; acc[i][1] = 0.0f;
    }

    mm_half(Q, K, C_, C_, C_ / 64, smem, acc, tid);

    const int w = tid >> 6, l = tid & 63, fr = l & 15, fq = l >> 4;
    const int wm = (w & 1) << 6, wn = (w >> 1) << 5;
    __syncthreads();                    // core done before bounce reuse
#pragma unroll
    for (int i = 0; i < 4; ++i)
#pragma unroll
        for (int r = 0; r < 4; ++r) {
            const int lm = wm + i * 16 + fq * 4 + r;
            const int m = m0 + lm;
#pragma unroll
            for (int j = 0; j < 2; ++j) {
                const int ls = wn + j * 16 + fr;
                const int s = s0 + ls;
                float e = (s <= m) ? __expf(acc[i][j][r] * 0.03125f) : 0.f;
                smem[lm * 72 + ls] = f2bf(e);
            }
        }
    __syncthreads();
    // att store: 128 rows x 64 cols = 1024 uint4, 4/thread
    u16* att = wsbase + att_off[b] + (size_t)m0 * T_ + s0;
#pragma unroll
    for (int p = 0; p < 4; ++p) {
        const int idx = p * 256 + tid;
        const int row = idx >> 3, c = idx & 7;
        uint4 val = *(const uint4*)&smem[row * 72 + c * 8];
        *(uint4*)(att + (size_t)row * T_ + c * 8) = val;
    }
    // 64-col partial row-sums (bf16-rounded P, matching what pv reads):
    // 2 threads/row (32 elems each), pair-shfl, one atomic per row.
    {
        const int r2 = tid >> 1, half = tid & 1;
        const u16* rowp = &smem[r2 * 72 + half * 32];
        float ssum = 0.f;
#pragma unroll
        for (int e = 0; e < 32; ++e) ssum += bf2f(rowp[e]);
        ssum += __shfl_xor(ssum, 1);
        if (!half) atomicAdd(&rowsum_g[b * 2048 + m0 + r2], ssum);
    }
}

// --------------------- O = (P v) / rowsum -----------------------------------
// grid (8, 16, 4). Rowsum read from rowsum_g (computed by scores) -->
// 32 MFMA per K-step instead of 40 (-20% MFMA).
// PAIR-BALANCED m-tile mapping (r4 counter-verified, -7.7 us): round-robin
// dispatch pairs block i with i+256 on one CU (z differs by 2, same y).
// by = (z<2 ? 15-y : y) makes the pair's K-chunks (16-y)+(y+1) = 17, uniform.
__global__ __launch_bounds__(256, 2) void pv_mfma(
    const u16* __restrict__ wsbase, const u16* __restrict__ vt,
    float* __restrict__ outp)
{
    const int b = blockIdx.z;
    const int n0 = blockIdx.x * 128;
    const int by = (blockIdx.z < 2) ? (15 - blockIdx.y) : blockIdx.y;  // pair-balance
    const int m0 = by * 128;
    __shared__ __align__(16) u16 smem[32768];  // 64 KB: dbuf staging | f32 bounce
    const u16* A  = wsbase + att_off[b] + (size_t)m0 * T_;
    const u16* Bp = vt + (size_t)b * C_ * T_ + (size_t)n0 * T_;
    const int tid = threadIdx.x;
    f32x4 acc[4][4];
#pragma unroll
    for (int i = 0; i < 4; ++i)
#pragma unroll
        for (int j = 0; j < 4; ++j) acc[i][j] = 0.0f;

    mm_core<false>(A, Bp, T_, T_, (m0 + 128) >> 6, smem, acc, nullptr, tid);

    const int w = tid >> 6, l = tid & 63, fr = l & 15, fq = l >> 4;
    const int wm = (w & 1) << 6, wn = (w >> 1) << 6;
    float* fb = (float*)smem;                  // 64 x 132 f32 bounce (33.8 KB)
#pragma unroll
    for (int p = 0; p < 2; ++p) {
        if ((w & 1) == p) {
#pragma unroll
            for (int i = 0; i < 4; ++i)
#pragma unroll
                for (int r = 0; r < 4; ++r) {
                    const int rr2 = i * 16 + fq * 4 + r;
                    const float inv = 1.0f / rowsum_g[b * 2048 + m0 + wm + rr2];
#pragma unroll
                    for (int j = 0; j < 4; ++j)
                        fb[rr2 * 132 + wn + j * 16 + fr] = acc[i][j][r] * inv;
                }
        }
        __syncthreads();
        const int rr = tid >> 5, cc = (tid & 31) * 4;
#pragma unroll
        for (int k2 = 0; k2 < 8; ++k2) {
            const int row = k2 * 8 + rr;
            float4 val = *(const float4*)&fb[row * 132 + cc];
            *(float4*)(outp + ((size_t)b * T_ + m0 + p * 64 + row) * C_ + n0 + cc) = val;
        }
        __syncthreads();
    }
}

extern "C" void kernel_launch(void* const* d_in, const int* in_sizes, int n_in,
                              void* d_out, int out_size, void* d_ws, size_t ws_size,
                              hipStream_t stream) {
    const float* x  = (const float*)d_in[0];
    const float* Wq = (const float*)d_in[1];
    const float* bq = (const float*)d_in[2];
    const float* Wk = (const float*)d_in[3];
    const float* bk = (const float*)d_in[4];
    const float* Wv = (const float*)d_in[5];
    const float* bv = (const float*)d_in[6];
    float* out = (float*)d_out;

    // workspace (80 MB):
    //   [ 0,16M) xb   -> dead after qkv; att batches 0,1 overlay
    //   [16,32M) q
    //   [32,48M) k
    //   [48,64M) vt   (v transposed [b][c][t])
    //   [64,70M) wt   -> dead after qkv; att batches 2,3 overlay [64,80M)
    char* ws = (char*)d_ws;
    u16* xb   = (u16*)ws;
    u16* q    = (u16*)(ws + (16ull << 20));
    u16* k    = (u16*)(ws + (32ull << 20));
    u16* vt   = (u16*)(ws + (48ull << 20));
    u16* wt   = (u16*)(ws + (64ull << 20));
    u16* attb = (u16*)ws;   // att_off[] indexes from workspace base

    cvt_all <<<8962, 256, 0, stream>>>(x, Wq, Wk, Wv, xb, wt);
    qkv_f   <<<1536, 256, 0, stream>>>(xb, wt, bq, bk, bv, q, k, vt);
    scores_h<<<1088, 256, 0, stream>>>(q, k, attb);
    pv_mfma <<<dim3(8, 16, 4), 256, 0, stream>>>(attb, vt, out);
}